// Round 10
// baseline (590.925 us; speedup 1.0000x reference)
//
#include <hip/hip_runtime.h>
#include <hip/hip_bf16.h>
#include <stdint.h>

// GPT2 attention forward, MI355X/gfx950.
// Pipeline: cast/transpose -> QKV GEMM (bf16 MFMA, fused bias, Q pre-scaled by
// 0.125*log2e) -> causal flash attention (exp2-domain softmax, T13 defer-max,
// LPT block order) -> proj GEMM (fused bias, fp32 out).
// B=4 S=2048 D=1280 H=20 HD=64; M=B*S=8192.

typedef unsigned short us;
typedef __attribute__((ext_vector_type(8))) short short8;   // 8 bf16 = 4 VGPR (MFMA A/B frag)
typedef __attribute__((ext_vector_type(4))) float f32x4;    // MFMA C/D frag

struct FalseT { static constexpr bool value = false; };
struct TrueT  { static constexpr bool value = true;  };

__device__ __forceinline__ us f2bf(float f) {
  union { float f; unsigned u; } v; v.f = f;
  unsigned u = v.u;
  unsigned r = (u + 0x7fffu + ((u >> 16) & 1u)) >> 16;   // RNE
  return (us)r;
}

// raw v_exp_f32: computes 2^x in one TRANS op; exp2(-inf)=0 in HW.
__device__ __forceinline__ float exp2_fast(float x) {
  float r; asm("v_exp_f32 %0, %1" : "=v"(r) : "v"(x)); return r;
}

// ---------------- cast x (fp32 -> bf16), vectorized ----------------
__global__ void cast_f32_to_bf16(const float* __restrict__ in, us* __restrict__ out, int n4) {
  int i = blockIdx.x * blockDim.x + threadIdx.x;
  if (i >= n4) return;
  float4 f = reinterpret_cast<const float4*>(in)[i];
  ushort4 o;
  o.x = f2bf(f.x); o.y = f2bf(f.y); o.z = f2bf(f.z); o.w = f2bf(f.w);
  reinterpret_cast<ushort4*>(out)[i] = o;
}

// ---------------- transpose + cast: in[R][C] fp32 -> out[C][R] bf16 ----------------
__global__ void transpose_cast(const float* __restrict__ in, us* __restrict__ out, int R, int C) {
  __shared__ float tile[32][33];
  int c0 = blockIdx.x * 32, r0 = blockIdx.y * 32;
  int x = threadIdx.x, y0 = threadIdx.y;       // 32 x 8
#pragma unroll
  for (int dy = 0; dy < 32; dy += 8)
    tile[y0 + dy][x] = in[(size_t)(r0 + y0 + dy) * C + c0 + x];
  __syncthreads();
#pragma unroll
  for (int dy = 0; dy < 32; dy += 8)
    out[(size_t)(c0 + y0 + dy) * R + r0 + x] = f2bf(tile[x][y0 + dy]);
}

// ---------------- GEMM: C[M][N] = A[M][K] * BT[N][K]^T + bias, bf16 MFMA ----------------
// m97-class structure: 128x128 tile, BK=32, 4 waves (2x2), double-buffered
// global_load_lds width=16, 16 MFMA + 8 ds_read_b128 per K-step.
// T1 XCD swizzle (grid blocks % 8 == 0 at both call sites -> bijective):
// each XCD gets contiguous tile rows -> A-panel reuse in its private L2.
// QSCALE: multiply cols < 1280 (the Q block of QKV) by 0.125*log2e so the
// attention softmax can run in the exp2 domain with no per-element scale.
template <int OUT_BF16, int QSCALE>
__global__ __launch_bounds__(256) void gemm_bt(
    const us* __restrict__ A, const us* __restrict__ BT,
    const float* __restrict__ bias, void* __restrict__ Cout,
    int M, int N, int K) {
  __shared__ us Ash[2][128 * 32] __attribute__((aligned(16)));
  __shared__ us Bsh[2][128 * 32] __attribute__((aligned(16)));

  const int tid = threadIdx.x;
  const int lane = tid & 63;
  const int wave = tid >> 6;

  const int nwg  = gridDim.x * gridDim.y;
  const int flat = blockIdx.y * gridDim.x + blockIdx.x;     // HW dispatch index (x fastest)
  const int swz  = (flat & 7) * (nwg >> 3) + (flat >> 3);   // contiguous chunk per XCD
  const int m0 = (swz / gridDim.x) * 128;
  const int n0 = (swz % gridDim.x) * 128;

  const int wr = wave >> 1, wc = wave & 1;
  const int lrow = lane & 15, lk = lane >> 4;

  f32x4 acc[4][4];
#pragma unroll
  for (int i = 0; i < 4; i++)
#pragma unroll
    for (int j = 0; j < 4; j++) acc[i][j] = (f32x4){0.f, 0.f, 0.f, 0.f};

  const int nt = K >> 5;

  auto stage = [&](const us* __restrict__ g, int rbase, int k0, us* lds) {
#pragma unroll
    for (int r = 0; r < 2; r++) {
      int c = r * 256 + tid;                    // chunk id (16B chunks)
      int row = c >> 2, seg = c & 3;
      const us* gp = g + (size_t)(rbase + row) * K + k0 + seg * 8;
      us* lp = lds + (size_t)(r * 256 + wave * 64) * 8;   // wave-uniform base; HW adds lane*16B
      __builtin_amdgcn_global_load_lds(
          (const __attribute__((address_space(1))) void*)gp,
          (__attribute__((address_space(3))) void*)lp, 16, 0, 0);
    }
  };

  stage(A, m0, 0, Ash[0]);
  stage(BT, n0, 0, Bsh[0]);
  __syncthreads();

  int cur = 0;
  for (int t = 0; t < nt; t++) {
    if (t + 1 < nt) {
      stage(A, m0, (t + 1) * 32, Ash[cur ^ 1]);
      stage(BT, n0, (t + 1) * 32, Bsh[cur ^ 1]);
    }
    const us* Ab = Ash[cur];
    const us* Bb = Bsh[cur];
    short8 a[4], b[4];
#pragma unroll
    for (int rb = 0; rb < 4; rb++)
      a[rb] = *(const short8*)(Ab + (wr * 64 + rb * 16 + lrow) * 32 + lk * 8);
#pragma unroll
    for (int cb = 0; cb < 4; cb++)
      b[cb] = *(const short8*)(Bb + (wc * 64 + cb * 16 + lrow) * 32 + lk * 8);
#pragma unroll
    for (int rb = 0; rb < 4; rb++)
#pragma unroll
      for (int cb = 0; cb < 4; cb++)
        acc[rb][cb] = __builtin_amdgcn_mfma_f32_16x16x32_bf16(a[rb], b[cb], acc[rb][cb], 0, 0, 0);
    __syncthreads();   // drains vmcnt (next-tile loads) + lgkmcnt, guards buffer reuse
    cur ^= 1;
  }

  // epilogue: C/D layout col=lane&15, row=(lane>>4)*4+j  [m89/m91 verified]
  float bv[4];
#pragma unroll
  for (int cb = 0; cb < 4; cb++) bv[cb] = bias[n0 + wc * 64 + cb * 16 + lrow];
#pragma unroll
  for (int rb = 0; rb < 4; rb++)
#pragma unroll
    for (int cb = 0; cb < 4; cb++)
#pragma unroll
      for (int j = 0; j < 4; j++) {
        int row = m0 + wr * 64 + rb * 16 + lk * 4 + j;
        int col = n0 + wc * 64 + cb * 16 + lrow;
        float v = acc[rb][cb][j] + bv[cb];
        if (QSCALE && col < 1280) v *= 0.18033688f;   // 0.125 * log2(e)
        if (OUT_BF16)
          ((us*)Cout)[(size_t)row * N + col] = f2bf(v);
        else
          ((float*)Cout)[(size_t)row * N + col] = v;
      }
}

// ---------------- causal flash attention ----------------
// grid flat = 1280 blocks (16 qt x 20 h x 4 b), block 256 = 4 waves; each wave
// owns 32 q-rows. T1 XCD swizzle: 160 contiguous blocks per XCD = 10 complete
// (h,b) groups -> each head's 512KB K/V panel L2-resident on one XCD.
// LPT order: qt = 15-(swz&15) dispatches longest blocks (16 tiles) first so
// short blocks backfill the scheduling tail (1280 blocks > ~768 resident).
// qkv: bf16 [8192][3840], Q at col h*64 (pre-scaled by 0.125*log2e),
// K at 1280+h*64, V at 2560+h*64. Softmax in exp2 domain, T13 defer-max
// (skip O/l rescale unless a row max grew > 8; P bounded by 2^8, bf16-safe).
// LDS aliasing: Ks[128][72] and Ps[4][32][136] share union buffer U (mid-tile
// barrier separates lifetimes). 52,224 B -> 3 blocks/CU (12 waves).
// K-frag ds_reads interleaved with MFMAs: peak VGPR ~159 < the 170 cap.
__global__ __launch_bounds__(256, 3) void attn_fwd(const us* __restrict__ qkv,
                                                   us* __restrict__ outb) {
  const int flat = (blockIdx.z * gridDim.y + blockIdx.y) * gridDim.x + blockIdx.x;
  const int swz  = (flat & 7) * 160 + (flat >> 3);   // 1280 blocks, bijective
  const int qt = 15 - (swz & 15), h = (swz >> 4) % 20, b = swz / 320;

  const int tid = threadIdx.x, lane = tid & 63, wave = tid >> 6;
  const int lrow = lane & 15, lk = lane >> 4;
  const int S = 2048, D3 = 3840, Dm = 1280;

  __shared__ us U[4 * 32 * 136] __attribute__((aligned(16)));   // Ks view: [128][72] (9216 us <= 17408)
  __shared__ us VTs[64][136]    __attribute__((aligned(16)));   // V transposed [d][k], +8 pad

  us* Ksb = U;                        // [128][72] during staging + QK^T
  us* Psw = U + wave * 32 * 136;      // per-wave [32][136] after the mid-tile barrier

  // Q fragments in registers: A-layout row=lane&15, k=(lane>>4)*8+i
  short8 qf[2][2];
  const size_t qrow0 = (size_t)(b * S + qt * 128 + wave * 32);
#pragma unroll
  for (int rb = 0; rb < 2; rb++)
#pragma unroll
    for (int ks = 0; ks < 2; ks++)
      qf[rb][ks] = *(const short8*)(qkv + (qrow0 + rb * 16 + lrow) * D3 + h * 64 + ks * 32 + lk * 8);

  f32x4 o[2][4];
  float m[2][4], l[2][4];
#pragma unroll
  for (int rb = 0; rb < 2; rb++) {
#pragma unroll
    for (int db = 0; db < 4; db++) o[rb][db] = (f32x4){0.f, 0.f, 0.f, 0.f};
#pragma unroll
    for (int j = 0; j < 4; j++) { m[rb][j] = -INFINITY; l[rb][j] = 0.f; }
  }

  // one K/V tile; DIAG (compile-time) = apply causal mask
  auto process = [&](int kt, auto diagC) {
    constexpr bool DIAG = decltype(diagC)::value;

    // ---- issue K/V global loads to registers (before barrier: overlaps
    //      other waves' prior-tile PV compute) ----
    short8 kreg[4], vreg0[2], vreg1[2];
#pragma unroll
    for (int r = 0; r < 4; r++) {
      int c = r * 256 + tid;
      int row = c >> 3, seg = c & 7;
      kreg[r] = *(const short8*)(qkv + (size_t)(b * S + kt * 128 + row) * D3 + h * 64 + seg * 8 + 1280);
    }
#pragma unroll
    for (int t = 0; t < 2; t++) {
      int idx = t * 256 + tid;                       // 512 tasks
      int rp  = (idx & 7) | ((idx >> 6) << 3);       // row-pair 0..63
      int seg = (idx >> 3) & 7;
      size_t gro = (size_t)(b * S + kt * 128 + 2 * rp) * D3 + h * 64 + seg * 8 + 2560;
      vreg0[t] = *(const short8*)(qkv + gro);
      vreg1[t] = *(const short8*)(qkv + gro + D3);
    }

    __syncthreads();   // prior tile's Ps(PV) reads + VTs reads done before overwrite

    // ---- ds_write K[128][72-stride] row-major (b128) ----
#pragma unroll
    for (int r = 0; r < 4; r++) {
      int c = r * 256 + tid;
      int row = c >> 3, seg = c & 7;
      *(short8*)&Ksb[row * 72 + seg * 8] = kreg[r];
    }
    // ---- ds_write V transposed, u32-packed, i rotated by seg ----
    // bank = 4*((i+seg)&7) + (lane&7) (mod 32) -> exactly 2 lanes/bank = free
#pragma unroll
    for (int t = 0; t < 2; t++) {
      int idx = t * 256 + tid;
      int rp  = (idx & 7) | ((idx >> 6) << 3);
      int seg = (idx >> 3) & 7;
#pragma unroll
      for (int i = 0; i < 8; i++) {
        int ii = (i + seg) & 7;
        unsigned val = (unsigned)(us)vreg0[t][ii] | ((unsigned)(us)vreg1[t][ii] << 16);
        *(unsigned*)&VTs[seg * 8 + ii][2 * rp] = val;
      }
    }
    __syncthreads();

    // S = Q K^T (128 k-cols per wave-row-block), K-dim = 64 = 2 MFMA steps.
    // kf reads interleaved with MFMAs: only 1 kf (4 VGPR) live at a time.
    f32x4 s[2][8];
#pragma unroll
    for (int rb = 0; rb < 2; rb++)
#pragma unroll
      for (int cb = 0; cb < 8; cb++) s[rb][cb] = (f32x4){0.f, 0.f, 0.f, 0.f};
#pragma unroll
    for (int ks = 0; ks < 2; ks++) {
#pragma unroll
      for (int cb = 0; cb < 8; cb++) {
        short8 kf = *(const short8*)&Ksb[(cb * 16 + lrow) * 72 + ks * 32 + lk * 8];
#pragma unroll
        for (int rb = 0; rb < 2; rb++)
          s[rb][cb] = __builtin_amdgcn_mfma_f32_16x16x32_bf16(qf[rb][ks], kf, s[rb][cb], 0, 0, 0);
      }
    }

    __syncthreads();   // ALIASING FENCE: all waves' Ks reads drained (each wave's
                       // lgkmcnt(0) precedes s_barrier) before Ps writes reuse U

    // ---- softmax pass 1: row maxes + T13 defer-rescale vote ----
    float mx[2][4];
    bool need = false;
#pragma unroll
    for (int rb = 0; rb < 2; rb++) {
#pragma unroll
      for (int j = 0; j < 4; j++) {
        float mxv = -3.0e38f;
        if (DIAG) {
          int ql = wave * 32 + rb * 16 + lk * 4 + j;   // q row within 128-tile
#pragma unroll
          for (int cb = 0; cb < 8; cb++) {
            float sv = s[rb][cb][j];
            if ((cb * 16 + lrow) > ql) sv = -INFINITY;
            s[rb][cb][j] = sv;
            mxv = fmaxf(mxv, sv);
          }
        } else {
#pragma unroll
          for (int cb = 0; cb < 8; cb++) mxv = fmaxf(mxv, s[rb][cb][j]);
        }
#pragma unroll
        for (int off = 1; off < 16; off <<= 1)
          mxv = fmaxf(mxv, __shfl_xor(mxv, off, 64));   // row spans the 16-lane col group
        mx[rb][j] = mxv;
        need = need || (mxv > m[rb][j] + 8.0f);
      }
    }
    // ---- rescale O/l only when some row max grew past THR (wave-uniform) ----
    if (__any(need)) {
#pragma unroll
      for (int rb = 0; rb < 2; rb++)
#pragma unroll
        for (int j = 0; j < 4; j++) {
          float mn = fmaxf(m[rb][j], mx[rb][j]);
          float al = exp2_fast(m[rb][j] - mn);   // first tile: 2^(-inf)=0
          m[rb][j] = mn;
          l[rb][j] *= al;
#pragma unroll
          for (int db = 0; db < 4; db++) o[rb][db][j] *= al;
        }
    }
    // ---- pass 2: P = 2^(s-m) (<= 2^8 when deferred), l += rowsum, Ps write ----
#pragma unroll
    for (int rb = 0; rb < 2; rb++) {
#pragma unroll
      for (int j = 0; j < 4; j++) {
        float mj = m[rb][j];
        float rs = 0.f;
#pragma unroll
        for (int cb = 0; cb < 8; cb++) {
          float p = exp2_fast(s[rb][cb][j] - mj);    // masked -inf -> 0
          s[rb][cb][j] = p;
          rs += p;
        }
#pragma unroll
        for (int off = 1; off < 16; off <<= 1)
          rs += __shfl_xor(rs, off, 64);
        l[rb][j] += rs;
        // C/D layout -> A layout via per-wave LDS (same-wave DS ops lgkmcnt-ordered)
#pragma unroll
        for (int cb = 0; cb < 8; cb++)
          Psw[(rb * 16 + lk * 4 + j) * 136 + cb * 16 + lrow] = f2bf(s[rb][cb][j]);
      }
    }

    // O += P[32x128] * V[128x64]; vb reads interleaved per db
#pragma unroll
    for (int ks2 = 0; ks2 < 4; ks2++) {
      short8 pa[2];
#pragma unroll
      for (int rb = 0; rb < 2; rb++)
        pa[rb] = *(const short8*)&Psw[(rb * 16 + lrow) * 136 + ks2 * 32 + lk * 8];
#pragma unroll
      for (int db = 0; db < 4; db++) {
        short8 vb = *(const short8*)&VTs[db * 16 + lrow][ks2 * 32 + lk * 8];
#pragma unroll
        for (int rb = 0; rb < 2; rb++)
          o[rb][db] = __builtin_amdgcn_mfma_f32_16x16x32_bf16(pa[rb], vb, o[rb][db], 0, 0, 0);
      }
    }
  };

  for (int kt = 0; kt < qt; kt++) process(kt, FalseT{});   // off-diagonal: no mask
  process(qt, TrueT{});                                    // diagonal tile: causal mask

  // normalize + store bf16 [B*S][1280]
#pragma unroll
  for (int rb = 0; rb < 2; rb++)
#pragma unroll
    for (int j = 0; j < 4; j++) {
      float invl = 1.f / l[rb][j];
      size_t row = qrow0 + rb * 16 + lk * 4 + j;
#pragma unroll
      for (int db = 0; db < 4; db++)
        outb[row * Dm + h * 64 + db * 16 + lrow] = f2bf(o[rb][db][j] * invl);
    }
}

// ---------------- launch ----------------
extern "C" void kernel_launch(void* const* d_in, const int* in_sizes, int n_in,
                              void* d_out, int out_size, void* d_ws, size_t ws_size,
                              hipStream_t stream) {
  const float* x      = (const float*)d_in[0];   // [4,2048,1280]
  const float* w_attn = (const float*)d_in[1];   // [1280,3840]
  const float* b_attn = (const float*)d_in[2];   // [3840]
  const float* w_proj = (const float*)d_in[3];   // [1280,1280]
  const float* b_proj = (const float*)d_in[4];   // [1280]
  float* out = (float*)d_out;                    // [8192,1280] fp32

  // ws layout high-water mark. If the harness workspace is smaller, DO NOT
  // launch (OOB staging writes would kill the container); leaving d_out
  // poisoned gives a clean, diagnosable "incorrect output" instead.
  const size_t WS_NEED = 96993280;
  if (ws_size < WS_NEED) return;

  char* ws = (char*)d_ws;
  // ws layout (bytes); attnb overlaps xb (xb dead after QKV GEMM).
  us* xb    = (us*)(ws);                  // 8192*1280 bf16 = 20,971,520
  us* attnb = (us*)(ws);                  // 8192*1280 bf16 (reuse of xb)
  us* wqkvT = (us*)(ws + 20971520);       // [3840][1280] bf16 = 9,830,400
  us* wpT   = (us*)(ws + 30801920);       // [1280][1280] bf16 = 3,276,800
  us* qkvb  = (us*)(ws + 34078720);       // [8192][3840] bf16 = 62,914,560

  cast_f32_to_bf16<<<10240, 256, 0, stream>>>(x, xb, 2621440);
  transpose_cast<<<dim3(120, 40), dim3(32, 8), 0, stream>>>(w_attn, wqkvT, 1280, 3840);
  transpose_cast<<<dim3(40, 40), dim3(32, 8), 0, stream>>>(w_proj, wpT, 1280, 1280);

  gemm_bt<1, 1><<<dim3(30, 64), 256, 0, stream>>>(xb, wqkvT, b_attn, qkvb, 8192, 3840, 1280);
  attn_fwd<<<dim3(16, 20, 4), 256, 0, stream>>>(qkvb, attnb);
  gemm_bt<0, 0><<<dim3(10, 64), 256, 0, stream>>>(attnb, wpT, b_proj, out, 8192, 1280, 1280);
}